// Round 17
// baseline (10282.639 us; speedup 1.0000x reference)
//
#include <hip/hip_runtime.h>

#define H 64
#define T_STEPS 2048
#define NBATCH 16          // batch columns per block (MFMA N dimension)
#define NBLK   16          // grid: 256 batches / 16

typedef _Float16 f16x8 __attribute__((ext_vector_type(8)));
typedef float    f32x4 __attribute__((ext_vector_type(4)));

__device__ __forceinline__ float sigmoid_f(float x) {
    return 1.0f / (1.0f + __expf(-x));
}
__device__ __forceinline__ float tanh_f(float x) {
    return 2.0f / (1.0f + __expf(-2.0f * x)) - 1.0f;
}

// ---- prep: reorder weights to cell-major rows (rr = 4*cell + gate) and
// convert fp32 -> f16 into d_ws. Layout (f16 elems):
//   [0,16384)       W0 = Whh0   rows 256 x 64
//   [16384, 49152)  W1 = [Wih1 | Whh1] rows 256 x 128
//   [49152, 81920)  W2 = [Wih2 | Whh2] rows 256 x 128
__global__ __launch_bounds__(256)
void prep_w(const float* __restrict__ Whh0,
            const float* __restrict__ Wih1, const float* __restrict__ Whh1,
            const float* __restrict__ Wih2, const float* __restrict__ Whh2,
            _Float16* __restrict__ ws) {
    int i = blockIdx.x * 256 + threadIdx.x;
    if (i < 16384) {
        int rr = i >> 6, k = i & 63;
        int srow = (rr & 3) * 64 + (rr >> 2);
        ws[i] = (_Float16)Whh0[srow * 64 + k];
    } else if (i < 49152) {
        int j = i - 16384; int rr = j >> 7, k = j & 127;
        int srow = (rr & 3) * 64 + (rr >> 2);
        float v = (k < 64) ? Wih1[srow * 64 + k] : Whh1[srow * 64 + k - 64];
        ws[i] = (_Float16)v;
    } else if (i < 81920) {
        int j = i - 49152; int rr = j >> 7, k = j & 127;
        int srow = (rr & 3) * 64 + (rr >> 2);
        float v = (k < 64) ? Wih2[srow * 64 + k] : Whh2[srow * 64 + k - 64];
        ws[i] = (_Float16)v;
    }
}

// R17: BATCHED MFMA LSTM. N=16 batches/block, 16 blocks. Evidence chain:
// f16 VALU MACs are ~8cyc slow-pipe (R13-R15); allocator caps live VGPRs
// at ~64-72 so fp32/large register sets spill (R1,R6,R8,R9,R11,R16); R16's
// N=1 MFMA wasted 15/16 of the tile and paid 16x-redundant activations.
// Here every MFMA column is a REAL batch -> zero redundancy, and A-frags
// stream per-phase from the f16 copy in d_ws (L2-resident, ~380 GB/s per
// block << per-XCD L2 BW) so nothing big needs registers or LDS.
// Maps (m89/R16-verified): C/D col=lane&15 (batch), row=4q+reg ->
// lane(n,q) of tile T owns cell 4T+q, gates i,f,g,o = acc[0..3], batch n.
// A[m=lane&15][k=q*8+j] -> lane reads W row (16T+n). B[k=q*8+j][n=lane&15]
// -> lane reads h[n][k-slice]. Waves 0-3: L0 (t=p), 4-7: L1 (t=p-1),
// 8-11: L2 (t=p-2); h triple-vector [h0|h1|h2] double-buffered in LDS;
// one barrier per phase.
__global__ __launch_bounds__(768)
void lstm3_b16(const float* __restrict__ x,
               const _Float16* __restrict__ ws,
               const float* __restrict__ Wih0,
               const float* __restrict__ bih0, const float* __restrict__ bhh0,
               const float* __restrict__ bih1, const float* __restrict__ bhh1,
               const float* __restrict__ bih2, const float* __restrict__ bhh2,
               const float* __restrict__ Wout, const float* __restrict__ bout,
               float* __restrict__ out)
{
    // hall[slot][n][0:64)=h0, [64:128)=h1, [128:192)=h2; stride 200 f16
    // (400 B = 4 banks mod 32 per n -> b128 reads are <=2-way, free).
    __shared__ __align__(16) _Float16 hall[2][NBATCH][200];
    __shared__ __align__(16) float biasr[3 * 256];   // [lay*256 + 4*cell+gate]
    __shared__ __align__(16) float wxr[512];         // [cell*8 + gate*2 + j]
    __shared__ __align__(16) float h2f[NBATCH][H];   // final h2, fp32

    const int tid  = threadIdx.x;
    const int b0   = blockIdx.x * NBATCH;
    const int wv   = tid >> 6;
    const int lay  = wv >> 2;            // 0,1,2 (wave-uniform)
    const int lane = tid & 63;
    const int n    = lane & 15;          // batch column
    const int q    = lane >> 4;          // quad

    // ---- init LDS ----
    {
        const int ly = tid >> 8, rr = tid & 255;
        const int gate = rr & 3, cell = rr >> 2;
        const float* bi = (ly == 0) ? bih0 : (ly == 1) ? bih1 : bih2;
        const float* bh = (ly == 0) ? bhh0 : (ly == 1) ? bhh1 : bhh2;
        biasr[tid] = bi[gate * 64 + cell] + bh[gate * 64 + cell];
    }
    if (tid < 512) {
        const int cell = tid >> 3, rem = tid & 7;
        const int gate = rem >> 1, j = rem & 1;
        wxr[tid] = Wih0[(gate * 64 + cell) * 2 + j];
    }
    for (int i = tid; i < 2 * NBATCH * 200 / 2; i += 768)
        ((unsigned int*)hall)[i] = 0u;   // zero both slots (f16 pairs)

    const _Float16* Wb = (lay == 0) ? ws
                       : (lay == 1) ? (ws + 16384) : (ws + 49152);
    float cst[4] = {0.f, 0.f, 0.f, 0.f};
    __syncthreads();

#pragma unroll 1
    for (int p = 0; p < T_STEPS + 2; ++p) {
        const int s  = (p + 1) & 1;      // read slot
        const int w  = p & 1;            // write slot
        const _Float16* hs = &hall[s][n][0];

        if (lay == 0) {
            if (p < T_STEPS) {
                float2 xt = *(const float2*)(x + ((size_t)(b0 + n) * T_STEPS + p) * 2);
                f16x8 bf0 = *(const f16x8*)(hs + q * 8);
                f16x8 bf1 = *(const f16x8*)(hs + 32 + q * 8);
#pragma unroll
                for (int i = 0; i < 4; ++i) {
                    const int T = (wv & 3) * 4 + i;
                    const int cq = 4 * T + q;
                    const _Float16* ap = Wb + (16 * T + n) * 64 + q * 8;
                    f16x8 a0 = *(const f16x8*)(ap);
                    f16x8 a1 = *(const f16x8*)(ap + 32);
                    f32x4 acc = *(const f32x4*)&biasr[cq * 4];
                    acc = __builtin_amdgcn_mfma_f32_16x16x32_f16(a0, bf0, acc, 0, 0, 0);
                    acc = __builtin_amdgcn_mfma_f32_16x16x32_f16(a1, bf1, acc, 0, 0, 0);
                    f32x4 wa = *(const f32x4*)&wxr[cq * 8];
                    f32x4 wb2 = *(const f32x4*)&wxr[cq * 8 + 4];
                    acc[0] += wa[0] * xt.x + wa[1] * xt.y;
                    acc[1] += wa[2] * xt.x + wa[3] * xt.y;
                    acc[2] += wb2[0] * xt.x + wb2[1] * xt.y;
                    acc[3] += wb2[2] * xt.x + wb2[3] * xt.y;
                    float gi = sigmoid_f(acc[0]), gf = sigmoid_f(acc[1]);
                    float gg = tanh_f(acc[2]),    go = sigmoid_f(acc[3]);
                    cst[i] = gf * cst[i] + gi * gg;
                    float hh = go * tanh_f(cst[i]);
                    hall[w][n][cq] = (_Float16)hh;
                }
            }
        } else if (lay == 1) {
            if (p >= 1 && p <= T_STEPS) {
                f16x8 bf0 = *(const f16x8*)(hs + q * 8);          // [h0|h1]
                f16x8 bf1 = *(const f16x8*)(hs + 32 + q * 8);
                f16x8 bf2 = *(const f16x8*)(hs + 64 + q * 8);
                f16x8 bf3 = *(const f16x8*)(hs + 96 + q * 8);
#pragma unroll
                for (int i = 0; i < 4; ++i) {
                    const int T = (wv & 3) * 4 + i;
                    const int cq = 4 * T + q;
                    const _Float16* ap = Wb + (16 * T + n) * 128 + q * 8;
                    f16x8 a0 = *(const f16x8*)(ap);
                    f16x8 a1 = *(const f16x8*)(ap + 32);
                    f16x8 a2 = *(const f16x8*)(ap + 64);
                    f16x8 a3 = *(const f16x8*)(ap + 96);
                    f32x4 acc = *(const f32x4*)&biasr[256 + cq * 4];
                    acc = __builtin_amdgcn_mfma_f32_16x16x32_f16(a0, bf0, acc, 0, 0, 0);
                    acc = __builtin_amdgcn_mfma_f32_16x16x32_f16(a1, bf1, acc, 0, 0, 0);
                    acc = __builtin_amdgcn_mfma_f32_16x16x32_f16(a2, bf2, acc, 0, 0, 0);
                    acc = __builtin_amdgcn_mfma_f32_16x16x32_f16(a3, bf3, acc, 0, 0, 0);
                    float gi = sigmoid_f(acc[0]), gf = sigmoid_f(acc[1]);
                    float gg = tanh_f(acc[2]),    go = sigmoid_f(acc[3]);
                    cst[i] = gf * cst[i] + gi * gg;
                    float hh = go * tanh_f(cst[i]);
                    hall[w][n][64 + cq] = (_Float16)hh;
                }
            }
        } else {
            if (p >= 2) {
                f16x8 bf0 = *(const f16x8*)(hs + 64 + q * 8);     // [h1|h2]
                f16x8 bf1 = *(const f16x8*)(hs + 96 + q * 8);
                f16x8 bf2 = *(const f16x8*)(hs + 128 + q * 8);
                f16x8 bf3 = *(const f16x8*)(hs + 160 + q * 8);
#pragma unroll
                for (int i = 0; i < 4; ++i) {
                    const int T = (wv & 3) * 4 + i;
                    const int cq = 4 * T + q;
                    const _Float16* ap = Wb + (16 * T + n) * 128 + q * 8;
                    f16x8 a0 = *(const f16x8*)(ap);
                    f16x8 a1 = *(const f16x8*)(ap + 32);
                    f16x8 a2 = *(const f16x8*)(ap + 64);
                    f16x8 a3 = *(const f16x8*)(ap + 96);
                    f32x4 acc = *(const f32x4*)&biasr[512 + cq * 4];
                    acc = __builtin_amdgcn_mfma_f32_16x16x32_f16(a0, bf0, acc, 0, 0, 0);
                    acc = __builtin_amdgcn_mfma_f32_16x16x32_f16(a1, bf1, acc, 0, 0, 0);
                    acc = __builtin_amdgcn_mfma_f32_16x16x32_f16(a2, bf2, acc, 0, 0, 0);
                    acc = __builtin_amdgcn_mfma_f32_16x16x32_f16(a3, bf3, acc, 0, 0, 0);
                    float gi = sigmoid_f(acc[0]), gf = sigmoid_f(acc[1]);
                    float gg = tanh_f(acc[2]),    go = sigmoid_f(acc[3]);
                    cst[i] = gf * cst[i] + gi * gg;
                    float hh = go * tanh_f(cst[i]);
                    hall[w][n][128 + cq] = (_Float16)hh;
                    if (p == T_STEPS + 1) h2f[n][cq] = hh;
                }
            }
        }
        __syncthreads();
    }

    // ---- projection: out[b0+n, :] = h2f[n] @ Wout^T + bout ----
    if (tid < 176) {
        const int o = tid >> 4;          // 0..10
        const int nn = tid & 15;
        float acc = bout[o];
#pragma unroll
        for (int jj = 0; jj < H; ++jj)
            acc += Wout[o * H + jj] * h2f[nn][jj];
        out[(b0 + nn) * 11 + o] = acc;
    }
}

extern "C" void kernel_launch(void* const* d_in, const int* in_sizes, int n_in,
                              void* d_out, int out_size, void* d_ws, size_t ws_size,
                              hipStream_t stream) {
    const float* x    = (const float*)d_in[0];
    const float* Wih0 = (const float*)d_in[1];
    const float* Whh0 = (const float*)d_in[2];
    const float* bih0 = (const float*)d_in[3];
    const float* bhh0 = (const float*)d_in[4];
    const float* Wih1 = (const float*)d_in[5];
    const float* Whh1 = (const float*)d_in[6];
    const float* bih1 = (const float*)d_in[7];
    const float* bhh1 = (const float*)d_in[8];
    const float* Wih2 = (const float*)d_in[9];
    const float* Whh2 = (const float*)d_in[10];
    const float* bih2 = (const float*)d_in[11];
    const float* bhh2 = (const float*)d_in[12];
    const float* Wout = (const float*)d_in[13];
    const float* bout = (const float*)d_in[14];
    float* out = (float*)d_out;
    _Float16* wsf = (_Float16*)d_ws;     // needs 160 KB

    prep_w<<<320, 256, 0, stream>>>(Whh0, Wih1, Whh1, Wih2, Whh2, wsf);
    lstm3_b16<<<NBLK, 768, 0, stream>>>(x, wsf, Wih0,
        bih0, bhh0, bih1, bhh1, bih2, bhh2,
        Wout, bout, out);
}

// Round 18
// 6274.308 us; speedup vs baseline: 1.6388x; 1.6388x over previous
//
#include <hip/hip_runtime.h>

#define H 64
#define T_STEPS 2048
#define NBATCH 16
#define NBLK   16
#define HSTR   202   // f16 stride: 101 dwords === 5 (mod 32) -> <=2-way LDS conflicts (free)

typedef _Float16 f16x8 __attribute__((ext_vector_type(8)));
typedef float    f32x4 __attribute__((ext_vector_type(4)));

__device__ __forceinline__ float sigmoid_f(float x) {
    return 1.0f / (1.0f + __expf(-x));
}
__device__ __forceinline__ float tanh_f(float x) {
    return 2.0f / (1.0f + __expf(-2.0f * x)) - 1.0f;
}

// ---- prep: reorder weights cell-major (rr = 4*cell + gate), fp32 -> f16.
//   [0,16384)       W0 = Whh0          rows 256 x 64
//   [16384, 49152)  W1 = [Wih1|Whh1]   rows 256 x 128
//   [49152, 81920)  W2 = [Wih2|Whh2]   rows 256 x 128
__global__ __launch_bounds__(256)
void prep_w(const float* __restrict__ Whh0,
            const float* __restrict__ Wih1, const float* __restrict__ Whh1,
            const float* __restrict__ Wih2, const float* __restrict__ Whh2,
            _Float16* __restrict__ ws) {
    int i = blockIdx.x * 256 + threadIdx.x;
    if (i < 16384) {
        int rr = i >> 6, k = i & 63;
        int srow = (rr & 3) * 64 + (rr >> 2);
        ws[i] = (_Float16)Whh0[srow * 64 + k];
    } else if (i < 49152) {
        int j = i - 16384; int rr = j >> 7, k = j & 127;
        int srow = (rr & 3) * 64 + (rr >> 2);
        float v = (k < 64) ? Wih1[srow * 64 + k] : Whh1[srow * 64 + k - 64];
        ws[i] = (_Float16)v;
    } else if (i < 81920) {
        int j = i - 49152; int rr = j >> 7, k = j & 127;
        int srow = (rr & 3) * 64 + (rr >> 2);
        float v = (k < 64) ? Wih2[srow * 64 + k] : Whh2[srow * 64 + k - 64];
        ws[i] = (_Float16)v;
    }
}

// R18 = R17 (maps HW-verified: identical absmax) + three fixes from R17's
// counters: (1) A-frags pinned in AGPRs ("+a" asm; MFMA reads AGPR natively,
// allocator has never capped AGPRs) -> zero in-loop weight traffic
// (R17 FETCH=2.8GB); (2) hall stride 200->202 f16 kills the 8-way bank
// conflicts (R17 SQ_LDS_BANK_CONFLICT=8.4M); (3) x[p+1] prefetched across
// the barrier. Expected bottleneck: trans pipe, 3072 updates x 10 trans
// / 4 SIMDs ~ 960 cyc/phase.
__global__ __launch_bounds__(768)
void lstm3_ag(const float* __restrict__ x,
              const _Float16* __restrict__ ws,
              const float* __restrict__ Wih0,
              const float* __restrict__ bih0, const float* __restrict__ bhh0,
              const float* __restrict__ bih1, const float* __restrict__ bhh1,
              const float* __restrict__ bih2, const float* __restrict__ bhh2,
              const float* __restrict__ Wout, const float* __restrict__ bout,
              float* __restrict__ out)
{
    __shared__ __align__(16) _Float16 hall[2][NBATCH][HSTR];
    __shared__ __align__(16) float biasr[3 * 256];
    __shared__ __align__(16) float wxr[512];
    __shared__ __align__(16) float h2f[NBATCH][H];

    const int tid  = threadIdx.x;
    const int b0   = blockIdx.x * NBATCH;
    const int wv   = tid >> 6;
    const int lay  = wv >> 2;            // wave-uniform 0,1,2
    const int lane = tid & 63;
    const int n    = lane & 15;          // batch column
    const int q    = lane >> 4;          // quad

    // ---- init LDS ----
    {
        const int ly = tid >> 8, rr = tid & 255;
        const int gate = rr & 3, cell = rr >> 2;
        const float* bi = (ly == 0) ? bih0 : (ly == 1) ? bih1 : bih2;
        const float* bh = (ly == 0) ? bhh0 : (ly == 1) ? bhh1 : bhh2;
        biasr[tid] = bi[gate * 64 + cell] + bh[gate * 64 + cell];
    }
    if (tid < 512) {
        const int cell = tid >> 3, rem = tid & 7;
        const int gate = rem >> 1, j = rem & 1;
        wxr[tid] = Wih0[(gate * 64 + cell) * 2 + j];
    }
    for (int i = tid; i < 2 * NBATCH * HSTR / 2; i += 768)
        ((unsigned int*)hall)[i] = 0u;

    // ---- A-fragments -> AGPRs (per wave: 4 tiles x 4 frags = 64 AGPRs) ----
    const _Float16* Wb = (lay == 0) ? ws : (lay == 1) ? (ws + 16384) : (ws + 49152);
    const int rs = (lay == 0) ? 64 : 128;
    const int Tb = (wv & 3) * 4;
    f16x8 z = {};
    auto ldf = [&](int T, int j) -> f16x8 {
        return *(const f16x8*)(Wb + (16 * T + n) * rs + j * 32 + q * 8);
    };
    f16x8 F00 = ldf(Tb + 0, 0), F01 = ldf(Tb + 0, 1);
    f16x8 F02 = lay ? ldf(Tb + 0, 2) : z, F03 = lay ? ldf(Tb + 0, 3) : z;
    f16x8 F10 = ldf(Tb + 1, 0), F11 = ldf(Tb + 1, 1);
    f16x8 F12 = lay ? ldf(Tb + 1, 2) : z, F13 = lay ? ldf(Tb + 1, 3) : z;
    f16x8 F20 = ldf(Tb + 2, 0), F21 = ldf(Tb + 2, 1);
    f16x8 F22 = lay ? ldf(Tb + 2, 2) : z, F23 = lay ? ldf(Tb + 2, 3) : z;
    f16x8 F30 = ldf(Tb + 3, 0), F31 = ldf(Tb + 3, 1);
    f16x8 F32 = lay ? ldf(Tb + 3, 2) : z, F33 = lay ? ldf(Tb + 3, 3) : z;
    asm volatile("" : "+a"(F00), "+a"(F01), "+a"(F02), "+a"(F03));
    asm volatile("" : "+a"(F10), "+a"(F11), "+a"(F12), "+a"(F13));
    asm volatile("" : "+a"(F20), "+a"(F21), "+a"(F22), "+a"(F23));
    asm volatile("" : "+a"(F30), "+a"(F31), "+a"(F32), "+a"(F33));

    float cst[4] = {0.f, 0.f, 0.f, 0.f};
    float2 xtc = make_float2(0.f, 0.f), xtn = make_float2(0.f, 0.f);
    if (lay == 0)
        xtc = *(const float2*)(x + ((size_t)(b0 + n) * T_STEPS + 0) * 2);
    __syncthreads();

#pragma unroll 1
    for (int p = 0; p < T_STEPS + 2; ++p) {
        const int s = (p + 1) & 1;       // read slot
        const int w = p & 1;             // write slot
        const _Float16* hs = &hall[s][n][0];

        if (lay == 0) {
            if (p + 1 < T_STEPS)         // prefetch next x across the barrier
                xtn = *(const float2*)(x + ((size_t)(b0 + n) * T_STEPS + p + 1) * 2);
            if (p < T_STEPS) {
                f16x8 bf0 = *(const f16x8*)(hs + q * 8);
                f16x8 bf1 = *(const f16x8*)(hs + 32 + q * 8);
                auto job0 = [&](int i, f16x8 Fa, f16x8 Fb) {
                    const int T = Tb + i, cq = 4 * T + q;
                    f32x4 acc = *(const f32x4*)&biasr[cq * 4];
                    acc = __builtin_amdgcn_mfma_f32_16x16x32_f16(Fa, bf0, acc, 0, 0, 0);
                    acc = __builtin_amdgcn_mfma_f32_16x16x32_f16(Fb, bf1, acc, 0, 0, 0);
                    f32x4 wa = *(const f32x4*)&wxr[cq * 8];
                    f32x4 wb = *(const f32x4*)&wxr[cq * 8 + 4];
                    acc[0] += wa[0] * xtc.x + wa[1] * xtc.y;
                    acc[1] += wa[2] * xtc.x + wa[3] * xtc.y;
                    acc[2] += wb[0] * xtc.x + wb[1] * xtc.y;
                    acc[3] += wb[2] * xtc.x + wb[3] * xtc.y;
                    float gi = sigmoid_f(acc[0]), gf = sigmoid_f(acc[1]);
                    float gg = tanh_f(acc[2]),    go = sigmoid_f(acc[3]);
                    cst[i] = gf * cst[i] + gi * gg;
                    hall[w][n][cq] = (_Float16)(go * tanh_f(cst[i]));
                };
                job0(0, F00, F01); job0(1, F10, F11);
                job0(2, F20, F21); job0(3, F30, F31);
            }
            xtc = xtn;
        } else if (lay == 1) {
            if (p >= 1 && p <= T_STEPS) {
                f16x8 bf0 = *(const f16x8*)(hs + q * 8);         // [h0|h1]
                f16x8 bf1 = *(const f16x8*)(hs + 32 + q * 8);
                f16x8 bf2 = *(const f16x8*)(hs + 64 + q * 8);
                f16x8 bf3 = *(const f16x8*)(hs + 96 + q * 8);
                auto job1 = [&](int i, f16x8 Fa, f16x8 Fb, f16x8 Fc, f16x8 Fd) {
                    const int T = Tb + i, cq = 4 * T + q;
                    f32x4 acc = *(const f32x4*)&biasr[256 + cq * 4];
                    acc = __builtin_amdgcn_mfma_f32_16x16x32_f16(Fa, bf0, acc, 0, 0, 0);
                    acc = __builtin_amdgcn_mfma_f32_16x16x32_f16(Fb, bf1, acc, 0, 0, 0);
                    acc = __builtin_amdgcn_mfma_f32_16x16x32_f16(Fc, bf2, acc, 0, 0, 0);
                    acc = __builtin_amdgcn_mfma_f32_16x16x32_f16(Fd, bf3, acc, 0, 0, 0);
                    float gi = sigmoid_f(acc[0]), gf = sigmoid_f(acc[1]);
                    float gg = tanh_f(acc[2]),    go = sigmoid_f(acc[3]);
                    cst[i] = gf * cst[i] + gi * gg;
                    hall[w][n][64 + cq] = (_Float16)(go * tanh_f(cst[i]));
                };
                job1(0, F00, F01, F02, F03); job1(1, F10, F11, F12, F13);
                job1(2, F20, F21, F22, F23); job1(3, F30, F31, F32, F33);
            }
        } else {
            if (p >= 2) {
                f16x8 bf0 = *(const f16x8*)(hs + 64 + q * 8);    // [h1|h2]
                f16x8 bf1 = *(const f16x8*)(hs + 96 + q * 8);
                f16x8 bf2 = *(const f16x8*)(hs + 128 + q * 8);
                f16x8 bf3 = *(const f16x8*)(hs + 160 + q * 8);
                const bool last = (p == T_STEPS + 1);
                auto job2 = [&](int i, f16x8 Fa, f16x8 Fb, f16x8 Fc, f16x8 Fd) {
                    const int T = Tb + i, cq = 4 * T + q;
                    f32x4 acc = *(const f32x4*)&biasr[512 + cq * 4];
                    acc = __builtin_amdgcn_mfma_f32_16x16x32_f16(Fa, bf0, acc, 0, 0, 0);
                    acc = __builtin_amdgcn_mfma_f32_16x16x32_f16(Fb, bf1, acc, 0, 0, 0);
                    acc = __builtin_amdgcn_mfma_f32_16x16x32_f16(Fc, bf2, acc, 0, 0, 0);
                    acc = __builtin_amdgcn_mfma_f32_16x16x32_f16(Fd, bf3, acc, 0, 0, 0);
                    float gi = sigmoid_f(acc[0]), gf = sigmoid_f(acc[1]);
                    float gg = tanh_f(acc[2]),    go = sigmoid_f(acc[3]);
                    cst[i] = gf * cst[i] + gi * gg;
                    float hh = go * tanh_f(cst[i]);
                    hall[w][n][128 + cq] = (_Float16)hh;
                    if (last) h2f[n][cq] = hh;
                };
                job2(0, F00, F01, F02, F03); job2(1, F10, F11, F12, F13);
                job2(2, F20, F21, F22, F23); job2(3, F30, F31, F32, F33);
            }
        }
        __syncthreads();
    }

    // ---- projection: out[b0+n, :] = h2f[n] @ Wout^T + bout ----
    if (tid < 176) {
        const int o = tid >> 4;          // 0..10
        const int nn = tid & 15;
        float acc = bout[o];
#pragma unroll
        for (int jj = 0; jj < H; ++jj)
            acc += Wout[o * H + jj] * h2f[nn][jj];
        out[(b0 + nn) * 11 + o] = acc;
    }
}

extern "C" void kernel_launch(void* const* d_in, const int* in_sizes, int n_in,
                              void* d_out, int out_size, void* d_ws, size_t ws_size,
                              hipStream_t stream) {
    const float* x    = (const float*)d_in[0];
    const float* Wih0 = (const float*)d_in[1];
    const float* Whh0 = (const float*)d_in[2];
    const float* bih0 = (const float*)d_in[3];
    const float* bhh0 = (const float*)d_in[4];
    const float* Wih1 = (const float*)d_in[5];
    const float* Whh1 = (const float*)d_in[6];
    const float* bih1 = (const float*)d_in[7];
    const float* bhh1 = (const float*)d_in[8];
    const float* Wih2 = (const float*)d_in[9];
    const float* Whh2 = (const float*)d_in[10];
    const float* bih2 = (const float*)d_in[11];
    const float* bhh2 = (const float*)d_in[12];
    const float* Wout = (const float*)d_in[13];
    const float* bout = (const float*)d_in[14];
    float* out = (float*)d_out;
    _Float16* wsf = (_Float16*)d_ws;     // 160 KB used

    prep_w<<<320, 256, 0, stream>>>(Whh0, Wih1, Whh1, Wih2, Whh2, wsf);
    lstm3_ag<<<NBLK, 768, 0, stream>>>(x, wsf, Wih0,
        bih0, bhh0, bih1, bhh1, bih2, bhh2,
        Wout, bout, out);
}